// Round 6
// baseline (159.415 us; speedup 1.0000x reference)
//
#include <hip/hip_runtime.h>

// Adaptive separable conv (SepConv): out[b,c,y,x] = sum_i sum_j inp[b,c,y+i,x+j]*v[b,i,y,x]*h[b,j,y,x]
// B=2,C=3,H=W=256,K=51. fp32 in/out. No MFMA path (per-pixel weights; no fp32 MFMA on CDNA4).
//
// R6: per-MAC efficiency. R5 fixed the spill (VGPR=60, WRITE=output-only, 93us) but each
// rotation ds_read_b128 served only R=4 outputs (LDS ~50% of CU time, 19 extra conflict
// cyc/read) and 16 rotation movs rode every 80 FMAs (VALU density 71%).
// This version:
//  - R=8 outputs/thread, TILE 64x8: each window float4 feeds 32 MACs (LDS instrs/MAC halved).
//  - 3-slot circular window, inner loop = 4 iterations x 3 compile-time phases: ZERO movs,
//    all w/v/h indices static (templates fold), FMA density ~87%.
//  - Same allocator discipline as R5: one uniform region (52 virtual taps, tap 51 v=0-masked),
//    no conditionals in hot loop, unroll-1 outer loops, h loaded 2 taps at a time (~115 live).
// LDS 26.9KB (58x116); grid (4,32,6)=768 wg x 256 thr; NS=4 i-split (blocks 4/3/3/3).

namespace {
constexpr int KK = 51;
constexpr int NB = 2;
constexpr int NC = 3;
constexpr int HH = 256;
constexpr int WW = 256;
constexpr int IN_H = HH + KK - 1;   // 306
constexpr int IN_W = WW + KK - 1;   // 306

constexpr int TILE_W = 64;          // output cols per block
constexpr int TILE_H = 8;           // output rows per block
constexpr int NTX = 8;              // threads along x (each covers R=8 outputs)
constexpr int R = 8;
constexpr int NTY = 8;
constexpr int NS = 4;               // i-tap split (one block-range per wave)
constexpr int NTHREADS = NTX * NTY * NS;   // 256
constexpr int HALO_W = TILE_W + KK - 1;    // 114
constexpr int LDS_W = 116;          // 114 valid + 2 slack (loads reach col 115; never used in FMA)
constexpr int LDS_H = TILE_H + KK - 1;     // 58
constexpr int KSTRIDE = HH * WW;    // per-tap stride in v/h (65536)
}

__device__ __forceinline__ float fget(const float4 v, int i) {
  return (i == 0) ? v.x : (i == 1) ? v.y : (i == 2) ? v.z : v.w;
}

// One j-tap: t = sum_ib v[ib]*w[ib], acc += h*t. P = window phase, JJ = j within chunk.
// All indices fold to constants after unrolling (rx compile-time, P/JJ template).
template <int P, int JJ>
__device__ __forceinline__ void fma_jtap(const float4 (&v4)[4][2], const float4 (&w4)[4][3],
                                         const float4 ha, const float4 hb, float (&acc)[R]) {
#pragma unroll
  for (int rx = 0; rx < R; ++rx) {
    const int k  = rx + JJ;            // logical window index 0..10
    const int sl = (P + k / 4) % 3;    // physical slot
    const int cp = k & 3;
    const int vh = rx >> 2, vc = rx & 3;
    float tv = fget(v4[0][vh], vc) * fget(w4[0][sl], cp);
    tv = fmaf(fget(v4[1][vh], vc), fget(w4[1][sl], cp), tv);
    tv = fmaf(fget(v4[2][vh], vc), fget(w4[2][sl], cp), tv);
    tv = fmaf(fget(v4[3][vh], vc), fget(w4[3][sl], cp), tv);
    const float hv = (rx < 4) ? fget(ha, vc) : fget(hb, vc);
    acc[rx] = fmaf(hv, tv, acc[rx]);
  }
}

// One chunk of 4 j-taps at phase P; then refill the vacated slot P from LDS.
template <int P>
__device__ __forceinline__ void do_chunk(const float4 (&v4)[4][2], float4 (&w4)[4][3],
                                         const int (&woff)[4], int ldcol,
                                         const float* hp, float (&acc)[R],
                                         const float* smem) {
  const float4 h0a = *reinterpret_cast<const float4*>(hp);
  const float4 h0b = *reinterpret_cast<const float4*>(hp + 4);
  const float4 h1a = *reinterpret_cast<const float4*>(hp + KSTRIDE);
  const float4 h1b = *reinterpret_cast<const float4*>(hp + KSTRIDE + 4);
  fma_jtap<P, 0>(v4, w4, h0a, h0b, acc);
  const float4 h2a = *reinterpret_cast<const float4*>(hp + 2 * (size_t)KSTRIDE);
  const float4 h2b = *reinterpret_cast<const float4*>(hp + 2 * (size_t)KSTRIDE + 4);
  const float4 h3a = *reinterpret_cast<const float4*>(hp + 3 * (size_t)KSTRIDE);
  const float4 h3b = *reinterpret_cast<const float4*>(hp + 3 * (size_t)KSTRIDE + 4);
  fma_jtap<P, 1>(v4, w4, h1a, h1b, acc);
  fma_jtap<P, 2>(v4, w4, h2a, h2b, acc);
  fma_jtap<P, 3>(v4, w4, h3a, h3b, acc);
#pragma unroll
  for (int ib = 0; ib < 4; ++ib)
    w4[ib][P] = *reinterpret_cast<const float4*>(&smem[woff[ib] + ldcol]);
}

__global__ __launch_bounds__(NTHREADS, 1)
void sepconv_kernel(
    const float* __restrict__ inp,
    const float* __restrict__ vert,
    const float* __restrict__ horiz,
    float* __restrict__ out)
{
  __shared__ float lds[LDS_H * LDS_W];   // 26,912 B

  const int tid = threadIdx.x;
  const int tx  = tid & (NTX - 1);
  const int ty  = (tid >> 3) & (NTY - 1);
  const int s   = tid >> 6;                    // wave id: 0..3 (wave-uniform)

  const int x0 = blockIdx.x * TILE_W;
  const int y0 = blockIdx.y * TILE_H;
  const int bc = blockIdx.z;                   // 0..5
  const int b  = bc / NC;
  const int c  = bc % NC;

  // ---- Stage input tile: 1ch x 58 rows x 114 cols (float2). Cols 114-115 untouched (unused).
  {
    const float* src = inp + (((size_t)(b * NC + c)) * IN_H + y0) * IN_W + x0;
    constexpr int total2 = LDS_H * (HALO_W / 2);   // 58*57 = 3306
    for (int e = tid; e < total2; e += NTHREADS) {
      const int col2 = e % (HALO_W / 2);
      const int r    = e / (HALO_W / 2);
      const float2 v = *reinterpret_cast<const float2*>(src + (size_t)r * IN_W + col2 * 2);
      float* dst = &lds[r * LDS_W + col2 * 2];
      dst[0] = v.x; dst[1] = v.y;
    }
  }
  __syncthreads();

  const int lx = tx * R;                 // local LDS col base (32B aligned)
  const int xg = x0 + lx;                // global x of first output
  const int yg = y0 + ty;                // global y

  float acc[R];
#pragma unroll
  for (int rx = 0; rx < R; ++rx) acc[rx] = 0.f;

  // Deal 13 BI=4 tap-blocks (52 virtual taps; tap 51 masked) to 4 waves: 4/3/3/3.
  const int blk0 = (s == 0) ? 0 : (3 * s + 1);   // 0,4,7,10
  const int nblk = (s == 0) ? 4 : 3;

  const float* vbase = vert  + (((size_t)b * KK) * HH + yg) * WW + xg;
  const float* hbase = horiz + (((size_t)b * KK) * HH + yg) * WW + xg;

#pragma unroll 1
  for (int t = 0; t < nblk; ++t) {
    const int ibase = (blk0 + t) * 4;    // 0..48

    // Vertical weights + initial 3-slot windows for the 4 taps of this block.
    float4 v4[4][2];
    float4 w4[4][3];
    int    woff[4];
#pragma unroll
    for (int ib = 0; ib < 4; ++ib) {
      const int iv = ibase + ib;                 // <= 51
      const int ic = (iv <= 50) ? iv : 50;       // clamp row for masked tap
      float4 va = *reinterpret_cast<const float4*>(vbase + (size_t)ic * KSTRIDE);
      float4 vb = *reinterpret_cast<const float4*>(vbase + (size_t)ic * KSTRIDE + 4);
      if (iv > 50) { va = make_float4(0.f, 0.f, 0.f, 0.f); vb = va; }
      v4[ib][0] = va; v4[ib][1] = vb;
      woff[ib] = (ty + ic) * LDS_W;              // row <= 57
      const float4* p = reinterpret_cast<const float4*>(&lds[woff[ib] + lx]);
      w4[ib][0] = p[0]; w4[ib][1] = p[1]; w4[ib][2] = p[2];
    }

    const float* hp = hbase;             // walks 4 taps per chunk

#pragma unroll 1
    for (int cc = 0; cc < 4; ++cc) {     // 4 x 3 phases = 12 clean chunks (j = 0..47)
      const int base = lx + 12 * cc + 12;
      do_chunk<0>(v4, w4, woff, base + 0, hp, acc, lds); hp += 4 * (size_t)KSTRIDE;
      do_chunk<1>(v4, w4, woff, base + 4, hp, acc, lds); hp += 4 * (size_t)KSTRIDE;
      do_chunk<2>(v4, w4, woff, base + 8, hp, acc, lds); hp += 4 * (size_t)KSTRIDE;
    }

    // Epilogue: j = 48,49,50. Window = phase 0 layout, logical col0 = 48 (max idx 9).
    {
      const float4 e0a = *reinterpret_cast<const float4*>(hp);
      const float4 e0b = *reinterpret_cast<const float4*>(hp + 4);
      const float4 e1a = *reinterpret_cast<const float4*>(hp + KSTRIDE);
      const float4 e1b = *reinterpret_cast<const float4*>(hp + KSTRIDE + 4);
      const float4 e2a = *reinterpret_cast<const float4*>(hp + 2 * (size_t)KSTRIDE);
      const float4 e2b = *reinterpret_cast<const float4*>(hp + 2 * (size_t)KSTRIDE + 4);
      fma_jtap<0, 0>(v4, w4, e0a, e0b, acc);
      fma_jtap<0, 1>(v4, w4, e1a, e1b, acc);
      fma_jtap<0, 2>(v4, w4, e2a, e2b, acc);
    }
  }

  // ---- Reduce the 4 i-split partials (waves 1..3 -> LDS, wave 0 adds & stores)
  __syncthreads();   // all LDS inp reads done; safe to reuse (3*64*8*4B = 6KB)
  if (s > 0) {
    float* p = &lds[((s - 1) * 64 + ty * NTX + tx) * R];
#pragma unroll
    for (int rx = 0; rx < R; ++rx) p[rx] = acc[rx];
  }
  __syncthreads();
  if (s == 0) {
#pragma unroll
    for (int g = 0; g < 3; ++g) {
      const float* p = &lds[(g * 64 + ty * NTX + tx) * R];
#pragma unroll
      for (int rx = 0; rx < R; ++rx) acc[rx] += p[rx];
    }
    float* o = out + (((size_t)(b * NC + c)) * HH + yg) * WW + xg;
    *reinterpret_cast<float4*>(o)     = make_float4(acc[0], acc[1], acc[2], acc[3]);
    *reinterpret_cast<float4*>(o + 4) = make_float4(acc[4], acc[5], acc[6], acc[7]);
  }
}

extern "C" void kernel_launch(void* const* d_in, const int* in_sizes, int n_in,
                              void* d_out, int out_size, void* d_ws, size_t ws_size,
                              hipStream_t stream) {
  const float* inp   = (const float*)d_in[0];
  const float* vert  = (const float*)d_in[1];
  const float* horiz = (const float*)d_in[2];
  float* out = (float*)d_out;

  dim3 grid(WW / TILE_W, HH / TILE_H, NB * NC);   // 4 x 32 x 6 = 768 blocks x 256 threads
  sepconv_kernel<<<grid, NTHREADS, 0, stream>>>(inp, vert, horiz, out);
}

// Round 7
// 143.242 us; speedup vs baseline: 1.1129x; 1.1129x over previous
//
#include <hip/hip_runtime.h>

// Adaptive separable conv (SepConv): out[b,c,y,x] = sum_i sum_j inp[b,c,y+i,x+j]*v[b,i,y,x]*h[b,j,y,x]
// B=2,C=3,H=W=256,K=51. fp32 in/out. No MFMA path (per-pixel weights; no fp32 MFMA on CDNA4).
//
// R7: h via LDS. R6 (93us) was latency-bound on per-wave global h loads: 8 float4 loads/chunk
// with no VGPR headroom -> serialized vmcnt waits, ~9% per-wave issue. All 4 waves read
// IDENTICAL h (h doesn't depend on the i-split), so:
//  - Stage each 4-tap h chunk (8KB) once per block via global_load_lds (no reg roundtrip),
//    double-buffered; 4 waves march in barrier lockstep (uniform 4x13 STEPs; inactive
//    tap-block iterations stage+barrier but skip FMA). Global h traffic 1.04GB -> 320MB.
//  - h LDS layout: per-row rotation (slot c4=(q+row)&15) via pre-permuted DMA SOURCE
//    addresses (LDS stays linear for DMA); read hits the 8-touch/bank b128 floor.
//  - Stage issue at top of each STEP -> vmcnt(0) drain at the barrier covers the full
//    compute span (~320cy) of h-latency.
// Keeps R6: R=8, TILE 64x8, 3-slot windows (zero-mov rotation), 1.25 ops/MAC, unroll-1,
// launch_bounds(256,1). LDS 26.9KB inp + 16KB h = 43.3KB -> 3 blocks/CU = 12 waves/CU.

namespace {
constexpr int KK = 51;
constexpr int NB = 2;
constexpr int NC = 3;
constexpr int HH = 256;
constexpr int WW = 256;
constexpr int IN_H = HH + KK - 1;   // 306
constexpr int IN_W = WW + KK - 1;   // 306

constexpr int TILE_W = 64;          // output cols per block
constexpr int TILE_H = 8;           // output rows per block
constexpr int NTX = 8;              // threads along x (each covers R=8 outputs)
constexpr int R = 8;
constexpr int NTY = 8;
constexpr int NS = 4;               // i-tap split (one block-range per wave)
constexpr int NTHREADS = NTX * NTY * NS;   // 256
constexpr int HALO_W = TILE_W + KK - 1;    // 114
constexpr int LDS_W = 116;          // 114 valid + 2 slack
constexpr int LDS_H = TILE_H + KK - 1;     // 58
constexpr int KSTRIDE = HH * WW;    // per-tap stride in v/h (65536)
constexpr int HCH = 4 * TILE_H * TILE_W;   // 2048 floats per h chunk buffer
}

__device__ __forceinline__ float fget(const float4 v, int i) {
  return (i == 0) ? v.x : (i == 1) ? v.y : (i == 2) ? v.z : v.w;
}

// One j-tap: t = sum_ib v[ib]*w[ib], acc += h*t. P = window phase, JJ = j within chunk.
template <int P, int JJ>
__device__ __forceinline__ void fma_jtap(const float4 (&v4)[4][2], const float4 (&w4)[4][3],
                                         const float4 ha, const float4 hb, float (&acc)[R]) {
#pragma unroll
  for (int rx = 0; rx < R; ++rx) {
    const int k  = rx + JJ;            // logical window index 0..10
    const int sl = (P + k / 4) % 3;    // physical slot
    const int cp = k & 3;
    const int vh = rx >> 2, vc = rx & 3;
    float tv = fget(v4[0][vh], vc) * fget(w4[0][sl], cp);
    tv = fmaf(fget(v4[1][vh], vc), fget(w4[1][sl], cp), tv);
    tv = fmaf(fget(v4[2][vh], vc), fget(w4[2][sl], cp), tv);
    tv = fmaf(fget(v4[3][vh], vc), fget(w4[3][sl], cp), tv);
    const float hv = (rx < 4) ? fget(ha, vc) : fget(hb, vc);
    acc[rx] = fmaf(hv, tv, acc[rx]);
  }
}

// Full chunk (4 j-taps) at phase P; h from LDS buffer hb (off0/off1 = rotated row offsets);
// then refill vacated window slot P from the inp tile.
template <int P>
__device__ __forceinline__ void full_chunk(const float4 (&v4)[4][2], float4 (&w4)[4][3],
                                           const int (&woff)[4], int wcol,
                                           const float* hb, int off0, int off1,
                                           float (&acc)[R], const float* smem) {
  const float4 h0a = *reinterpret_cast<const float4*>(hb + off0);
  const float4 h0b = *reinterpret_cast<const float4*>(hb + off1);
  const float4 h1a = *reinterpret_cast<const float4*>(hb + 512 + off0);
  const float4 h1b = *reinterpret_cast<const float4*>(hb + 512 + off1);
  fma_jtap<P, 0>(v4, w4, h0a, h0b, acc);
  const float4 h2a = *reinterpret_cast<const float4*>(hb + 1024 + off0);
  const float4 h2b = *reinterpret_cast<const float4*>(hb + 1024 + off1);
  fma_jtap<P, 1>(v4, w4, h1a, h1b, acc);
  const float4 h3a = *reinterpret_cast<const float4*>(hb + 1536 + off0);
  const float4 h3b = *reinterpret_cast<const float4*>(hb + 1536 + off1);
  fma_jtap<P, 2>(v4, w4, h2a, h2b, acc);
  fma_jtap<P, 3>(v4, w4, h3a, h3b, acc);
#pragma unroll
  for (int ib = 0; ib < 4; ++ib)
    w4[ib][P] = *reinterpret_cast<const float4*>(&smem[woff[ib] + wcol]);
}

__global__ __launch_bounds__(NTHREADS, 1)
void sepconv_kernel(
    const float* __restrict__ inp,
    const float* __restrict__ vert,
    const float* __restrict__ horiz,
    float* __restrict__ out)
{
  __shared__ float lds[LDS_H * LDS_W];   // 26,912 B (inp tile; reused for reduction)
  __shared__ float hbuf[2 * HCH];        // 16,384 B (h double buffer)

  const int tid = threadIdx.x;
  const int tx  = tid & (NTX - 1);
  const int ty  = (tid >> 3) & (NTY - 1);
  const int s   = tid >> 6;                    // wave id: 0..3 (wave-uniform)

  const int x0 = blockIdx.x * TILE_W;
  const int y0 = blockIdx.y * TILE_H;
  const int bc = blockIdx.z;                   // 0..5
  const int b  = bc / NC;
  const int c  = bc % NC;

  // ---- Stage input tile: 1ch x 58 rows x 114 cols (float2). Cols 114-115 untouched.
  {
    const float* src = inp + (((size_t)(b * NC + c)) * IN_H + y0) * IN_W + x0;
    constexpr int total2 = LDS_H * (HALO_W / 2);   // 58*57 = 3306
    for (int e = tid; e < total2; e += NTHREADS) {
      const int col2 = e % (HALO_W / 2);
      const int r    = e / (HALO_W / 2);
      const float2 v = *reinterpret_cast<const float2*>(src + (size_t)r * IN_W + col2 * 2);
      float* dst = &lds[r * LDS_W + col2 * 2];
      dst[0] = v.x; dst[1] = v.y;
    }
  }

  // ---- h-staging precompute. Physical float4 slot p = r*256+tid:
  // jj=p>>7, row=(p&127)>>4, c4=p&15; slot holds global quad q=(c4-row)&15 (row rotation).
  const float* hblk = horiz + (((size_t)b * KK) * HH + y0) * WW + x0;
  int jj_[2], goff_[2], ldso_[2];
#pragma unroll
  for (int r = 0; r < 2; ++r) {
    const int p   = r * 256 + tid;
    const int jj  = p >> 7;
    const int rem = p & 127;
    const int row = rem >> 4;
    const int c4  = rem & 15;
    const int q   = (c4 - row) & 15;
    jj_[r]   = jj;
    goff_[r] = row * WW + q * 4;
    ldso_[r] = (r * 256 + (tid & ~63)) * 4;    // wave-uniform DMA dest base (floats)
  }
  auto stage = [&](int cc, int bufn) {
#pragma unroll
    for (int r = 0; r < 2; ++r) {
      const int j  = 4 * cc + jj_[r];
      const int jc = (j <= 50) ? j : 50;       // clamp (tap 51 data never read)
      const float* g = hblk + (size_t)jc * KSTRIDE + goff_[r];
      float* l = &hbuf[bufn * HCH + ldso_[r]];
      __builtin_amdgcn_global_load_lds((const __attribute__((address_space(1))) void*)g,
                                       (__attribute__((address_space(3))) void*)l, 16, 0, 0);
    }
  };

  stage(0, 0);          // prologue: h chunk cc=0 -> buf0
  __syncthreads();      // drains inp staging + chunk-0 DMA

  const int lx = tx * R;                 // local LDS col base (32B aligned)
  const int xg = x0 + lx;
  const int yg = y0 + ty;

  // Rotated h read offsets (invariant): row ty, logical quads 2tx, 2tx+1.
  const int off0 = ty * 64 + ((2 * tx + ty) & 15) * 4;
  const int off1 = ty * 64 + ((2 * tx + 1 + ty) & 15) * 4;

  float acc[R];
#pragma unroll
  for (int rx = 0; rx < R; ++rx) acc[rx] = 0.f;

  // Deal 13 BI=4 tap-blocks (52 virtual taps; tap 51 masked) to 4 waves: 4/3/3/3.
  const int blk0 = (s == 0) ? 0 : (3 * s + 1);   // 0,4,7,10
  const int nblk = (s == 0) ? 4 : 3;

  const float* vbase = vert + (((size_t)b * KK) * HH + yg) * WW + xg;

  int ccn = 1, buf = 0;   // next stage cc; current compute buffer

#pragma unroll 1
  for (int t = 0; t < 4; ++t) {          // uniform trip count for ALL waves (barriers!)
    const bool act = (t < nblk);
    float4 v4[4][2];
    float4 w4[4][3];
    int    woff[4];
    if (act) {
      const int ibase = (blk0 + t) * 4;
#pragma unroll
      for (int ib = 0; ib < 4; ++ib) {
        const int iv = ibase + ib;                 // <= 51
        const int ic = (iv <= 50) ? iv : 50;
        float4 va = *reinterpret_cast<const float4*>(vbase + (size_t)ic * KSTRIDE);
        float4 vb = *reinterpret_cast<const float4*>(vbase + (size_t)ic * KSTRIDE + 4);
        if (iv > 50) { va = make_float4(0.f, 0.f, 0.f, 0.f); vb = va; }
        v4[ib][0] = va; v4[ib][1] = vb;
        woff[ib] = (ty + ic) * LDS_W;              // row <= 57
        const float4* p = reinterpret_cast<const float4*>(&lds[woff[ib] + lx]);
        w4[ib][0] = p[0]; w4[ib][1] = p[1]; w4[ib][2] = p[2];
      }
    }

#pragma unroll 1
    for (int g = 0; g < 4; ++g) {        // 12 full chunks = 4 groups x 3 phases
      const int base = lx + 12 * g + 12;
      stage(ccn, buf ^ 1); ccn = (ccn == 12) ? 0 : ccn + 1;
      if (act) full_chunk<0>(v4, w4, woff, base + 0, hbuf + buf * HCH, off0, off1, acc, lds);
      __syncthreads(); buf ^= 1;
      stage(ccn, buf ^ 1); ccn = (ccn == 12) ? 0 : ccn + 1;
      if (act) full_chunk<1>(v4, w4, woff, base + 4, hbuf + buf * HCH, off0, off1, acc, lds);
      __syncthreads(); buf ^= 1;
      stage(ccn, buf ^ 1); ccn = (ccn == 12) ? 0 : ccn + 1;
      if (act) full_chunk<2>(v4, w4, woff, base + 8, hbuf + buf * HCH, off0, off1, acc, lds);
      __syncthreads(); buf ^= 1;
    }

    // Epilogue chunk (cc=12): j = 48,49,50; phase-0 window layout.
    stage(ccn, buf ^ 1); ccn = (ccn == 12) ? 0 : ccn + 1;
    if (act) {
      const float* hb = hbuf + buf * HCH;
      const float4 e0a = *reinterpret_cast<const float4*>(hb + off0);
      const float4 e0b = *reinterpret_cast<const float4*>(hb + off1);
      const float4 e1a = *reinterpret_cast<const float4*>(hb + 512 + off0);
      const float4 e1b = *reinterpret_cast<const float4*>(hb + 512 + off1);
      const float4 e2a = *reinterpret_cast<const float4*>(hb + 1024 + off0);
      const float4 e2b = *reinterpret_cast<const float4*>(hb + 1024 + off1);
      fma_jtap<0, 0>(v4, w4, e0a, e0b, acc);
      fma_jtap<0, 1>(v4, w4, e1a, e1b, acc);
      fma_jtap<0, 2>(v4, w4, e2a, e2b, acc);
    }
    __syncthreads(); buf ^= 1;
  }

  // ---- Reduce the 4 i-split partials (waves 1..3 -> LDS inp region, wave 0 adds & stores)
  if (s > 0) {
    float* p = &lds[((s - 1) * 64 + ty * NTX + tx) * R];
#pragma unroll
    for (int rx = 0; rx < R; ++rx) p[rx] = acc[rx];
  }
  __syncthreads();
  if (s == 0) {
#pragma unroll
    for (int g = 0; g < 3; ++g) {
      const float* p = &lds[(g * 64 + ty * NTX + tx) * R];
#pragma unroll
      for (int rx = 0; rx < R; ++rx) acc[rx] += p[rx];
    }
    float* o = out + (((size_t)(b * NC + c)) * HH + yg) * WW + xg;
    *reinterpret_cast<float4*>(o)     = make_float4(acc[0], acc[1], acc[2], acc[3]);
    *reinterpret_cast<float4*>(o + 4) = make_float4(acc[4], acc[5], acc[6], acc[7]);
  }
}

extern "C" void kernel_launch(void* const* d_in, const int* in_sizes, int n_in,
                              void* d_out, int out_size, void* d_ws, size_t ws_size,
                              hipStream_t stream) {
  const float* inp   = (const float*)d_in[0];
  const float* vert  = (const float*)d_in[1];
  const float* horiz = (const float*)d_in[2];
  float* out = (float*)d_out;

  dim3 grid(WW / TILE_W, HH / TILE_H, NB * NC);   // 4 x 32 x 6 = 768 blocks x 256 threads
  sepconv_kernel<<<grid, NTHREADS, 0, stream>>>(inp, vert, horiz, out);
}

// Round 8
// 143.106 us; speedup vs baseline: 1.1140x; 1.0009x over previous
//
#include <hip/hip_runtime.h>

// Adaptive separable conv (SepConv): out[b,c,y,x] = sum_i sum_j inp[b,c,y+i,x+j]*v[b,i,y,x]*h[b,j,y,x]
// B=2,C=3,H=W=256,K=51. fp32 in/out. No MFMA path (per-pixel weights; no fp32 MFMA on CDNA4).
//
// R8: counted-vmcnt pipeline (T4). R7 (73us, VALUBusy 40%) stalls on __syncthreads' implied
// s_waitcnt vmcnt(0): every chunk-step drains the DMA issued in that same step (cover = 1
// chunk span). Now: triple-buffered h (3x8KB), raw s_barrier + counted vmcnt(2) (the 2
// in-flight global_load_lds of stage(n+1) ride across the barrier; only the final step
// drains to 0). DMA cover = 2 chunk spans (~700cy >= L2 latency). Step body:
//   wait vmcnt(2); s_barrier; stage(n+2); compute(n).
// Cross-wave safety: each wave waits its OWN vmcnt before the barrier -> after the barrier
// every wave's stage(n) has landed; stage(n+2) overwrites the slot last read at n-1, whose
// readers all passed this barrier.
// Keeps R7: R=8, TILE 64x8, 3-slot zero-mov windows, h row-rotation layout (pre-permuted
// DMA source), 1.25 ops/MAC, unroll-1, launch_bounds(256,1).
// LDS 26.9KB inp + 24KB h = 50.9KB -> 3 blocks/CU = 12 waves/CU.

namespace {
constexpr int KK = 51;
constexpr int NB = 2;
constexpr int NC = 3;
constexpr int HH = 256;
constexpr int WW = 256;
constexpr int IN_H = HH + KK - 1;   // 306
constexpr int IN_W = WW + KK - 1;   // 306

constexpr int TILE_W = 64;          // output cols per block
constexpr int TILE_H = 8;           // output rows per block
constexpr int NTX = 8;              // threads along x (each covers R=8 outputs)
constexpr int R = 8;
constexpr int NTY = 8;
constexpr int NS = 4;               // i-tap split (one block-range per wave)
constexpr int NTHREADS = NTX * NTY * NS;   // 256
constexpr int HALO_W = TILE_W + KK - 1;    // 114
constexpr int LDS_W = 116;          // 114 valid + 2 slack
constexpr int LDS_H = TILE_H + KK - 1;     // 58
constexpr int KSTRIDE = HH * WW;    // per-tap stride in v/h (65536)
constexpr int HCH = 4 * TILE_H * TILE_W;   // 2048 floats per h chunk buffer
constexpr int NSTEPS = 52;          // 4 tap-blocks x 13 chunks
}

__device__ __forceinline__ float fget(const float4 v, int i) {
  return (i == 0) ? v.x : (i == 1) ? v.y : (i == 2) ? v.z : v.w;
}

// One j-tap: t = sum_ib v[ib]*w[ib], acc += h*t. P = window phase, JJ = j within chunk.
template <int P, int JJ>
__device__ __forceinline__ void fma_jtap(const float4 (&v4)[4][2], const float4 (&w4)[4][3],
                                         const float4 ha, const float4 hb, float (&acc)[R]) {
#pragma unroll
  for (int rx = 0; rx < R; ++rx) {
    const int k  = rx + JJ;            // logical window index 0..10
    const int sl = (P + k / 4) % 3;    // physical slot
    const int cp = k & 3;
    const int vh = rx >> 2, vc = rx & 3;
    float tv = fget(v4[0][vh], vc) * fget(w4[0][sl], cp);
    tv = fmaf(fget(v4[1][vh], vc), fget(w4[1][sl], cp), tv);
    tv = fmaf(fget(v4[2][vh], vc), fget(w4[2][sl], cp), tv);
    tv = fmaf(fget(v4[3][vh], vc), fget(w4[3][sl], cp), tv);
    const float hv = (rx < 4) ? fget(ha, vc) : fget(hb, vc);
    acc[rx] = fmaf(hv, tv, acc[rx]);
  }
}

// Full chunk (4 j-taps) at phase P; h from LDS buffer hb (off0/off1 = rotated row offsets);
// then refill vacated window slot P from the inp tile.
template <int P>
__device__ __forceinline__ void full_chunk(const float4 (&v4)[4][2], float4 (&w4)[4][3],
                                           const int (&woff)[4], int wcol,
                                           const float* hb, int off0, int off1,
                                           float (&acc)[R], const float* smem) {
  const float4 h0a = *reinterpret_cast<const float4*>(hb + off0);
  const float4 h0b = *reinterpret_cast<const float4*>(hb + off1);
  const float4 h1a = *reinterpret_cast<const float4*>(hb + 512 + off0);
  const float4 h1b = *reinterpret_cast<const float4*>(hb + 512 + off1);
  fma_jtap<P, 0>(v4, w4, h0a, h0b, acc);
  const float4 h2a = *reinterpret_cast<const float4*>(hb + 1024 + off0);
  const float4 h2b = *reinterpret_cast<const float4*>(hb + 1024 + off1);
  fma_jtap<P, 1>(v4, w4, h1a, h1b, acc);
  const float4 h3a = *reinterpret_cast<const float4*>(hb + 1536 + off0);
  const float4 h3b = *reinterpret_cast<const float4*>(hb + 1536 + off1);
  fma_jtap<P, 2>(v4, w4, h2a, h2b, acc);
  fma_jtap<P, 3>(v4, w4, h3a, h3b, acc);
#pragma unroll
  for (int ib = 0; ib < 4; ++ib)
    w4[ib][P] = *reinterpret_cast<const float4*>(&smem[woff[ib] + wcol]);
}

__global__ __launch_bounds__(NTHREADS, 1)
void sepconv_kernel(
    const float* __restrict__ inp,
    const float* __restrict__ vert,
    const float* __restrict__ horiz,
    float* __restrict__ out)
{
  __shared__ float lds[LDS_H * LDS_W];   // 26,912 B (inp tile; reused for reduction)
  __shared__ float hbuf[3 * HCH];        // 24,576 B (h triple buffer)

  const int tid = threadIdx.x;
  const int tx  = tid & (NTX - 1);
  const int ty  = (tid >> 3) & (NTY - 1);
  const int s   = tid >> 6;                    // wave id: 0..3 (wave-uniform)

  const int x0 = blockIdx.x * TILE_W;
  const int y0 = blockIdx.y * TILE_H;
  const int bc = blockIdx.z;                   // 0..5
  const int b  = bc / NC;
  const int c  = bc % NC;

  // ---- Stage input tile: 1ch x 58 rows x 114 cols (float2). Cols 114-115 untouched.
  {
    const float* src = inp + (((size_t)(b * NC + c)) * IN_H + y0) * IN_W + x0;
    constexpr int total2 = LDS_H * (HALO_W / 2);   // 58*57 = 3306
    for (int e = tid; e < total2; e += NTHREADS) {
      const int col2 = e % (HALO_W / 2);
      const int r    = e / (HALO_W / 2);
      const float2 v = *reinterpret_cast<const float2*>(src + (size_t)r * IN_W + col2 * 2);
      float* dst = &lds[r * LDS_W + col2 * 2];
      dst[0] = v.x; dst[1] = v.y;
    }
  }

  // ---- h-staging precompute. Physical float4 slot p = r*256+tid:
  // jj=p>>7, row=(p&127)>>4, c4=p&15; slot holds global quad q=(c4-row)&15 (row rotation).
  const float* hblk = horiz + (((size_t)b * KK) * HH + y0) * WW + x0;
  int jj_[2], goff_[2], ldso_[2];
#pragma unroll
  for (int r = 0; r < 2; ++r) {
    const int p   = r * 256 + tid;
    const int jj  = p >> 7;
    const int rem = p & 127;
    const int row = rem >> 4;
    const int c4  = rem & 15;
    const int q   = (c4 - row) & 15;
    jj_[r]   = jj;
    goff_[r] = row * WW + q * 4;
    ldso_[r] = (r * 256 + (tid & ~63)) * 4;    // wave-uniform DMA dest base (floats)
  }
  auto stage = [&](int cc, int bufn) {
#pragma unroll
    for (int r = 0; r < 2; ++r) {
      const int j  = 4 * cc + jj_[r];
      const int jc = (j <= 50) ? j : 50;       // clamp (tap 51 data never read)
      const float* g = hblk + (size_t)jc * KSTRIDE + goff_[r];
      float* l = &hbuf[bufn * HCH + ldso_[r]];
      __builtin_amdgcn_global_load_lds((const __attribute__((address_space(1))) void*)g,
                                       (__attribute__((address_space(3))) void*)l, 16, 0, 0);
    }
  };

  // Prologue: chunks 0,1 -> slots 0,1; full drain once (also covers inp ds_writes).
  stage(0, 0);
  stage(1, 1);
  __syncthreads();

  const int lx = tx * R;                 // local LDS col base (32B aligned)
  const int xg = x0 + lx;
  const int yg = y0 + ty;

  // Rotated h read offsets (invariant): row ty, logical quads 2tx, 2tx+1.
  const int off0 = ty * 64 + ((2 * tx + ty) & 15) * 4;
  const int off1 = ty * 64 + ((2 * tx + 1 + ty) & 15) * 4;

  float acc[R];
#pragma unroll
  for (int rx = 0; rx < R; ++rx) acc[rx] = 0.f;

  // Deal 13 BI=4 tap-blocks (52 virtual taps; tap 51 masked) to 4 waves: 4/3/3/3.
  const int blk0 = (s == 0) ? 0 : (3 * s + 1);   // 0,4,7,10
  const int nblk = (s == 0) ? 4 : 3;

  const float* vbase = vert + (((size_t)b * KK) * HH + yg) * WW + xg;

  // Pipeline state (all wave-uniform): nstep = chunk being computed; bcur = its hbuf slot;
  // ccn = cc of the chunk staged this step (= (nstep+2) % 13).
  int nstep = 0, bcur = 0, ccn = 2;

  // Step sync: counted vmcnt keeps stage(n+1)'s 2 DMA in flight across the barrier.
  // Only the final step drains to 0 (no younger stages exist to count past).
  auto syncstage = [&]() {
    if (nstep == NSTEPS - 1) {
      asm volatile("s_waitcnt vmcnt(0)" ::: "memory");
    } else {
      asm volatile("s_waitcnt vmcnt(2)" ::: "memory");
    }
    __builtin_amdgcn_s_barrier();
    if (nstep + 2 < NSTEPS) {
      stage(ccn, (bcur + 2) % 3);
      ccn = (ccn == 12) ? 0 : ccn + 1;
    }
  };
  auto adv = [&]() { bcur = (bcur + 1) % 3; ++nstep; };

#pragma unroll 1
  for (int t = 0; t < 4; ++t) {          // uniform trip count for ALL waves (barriers!)
    const bool act = (t < nblk);
    float4 v4[4][2];
    float4 w4[4][3];
    int    woff[4];
    if (act) {
      const int ibase = (blk0 + t) * 4;
#pragma unroll
      for (int ib = 0; ib < 4; ++ib) {
        const int iv = ibase + ib;                 // <= 51
        const int ic = (iv <= 50) ? iv : 50;
        float4 va = *reinterpret_cast<const float4*>(vbase + (size_t)ic * KSTRIDE);
        float4 vb = *reinterpret_cast<const float4*>(vbase + (size_t)ic * KSTRIDE + 4);
        if (iv > 50) { va = make_float4(0.f, 0.f, 0.f, 0.f); vb = va; }
        v4[ib][0] = va; v4[ib][1] = vb;
        woff[ib] = (ty + ic) * LDS_W;              // row <= 57
        const float4* p = reinterpret_cast<const float4*>(&lds[woff[ib] + lx]);
        w4[ib][0] = p[0]; w4[ib][1] = p[1]; w4[ib][2] = p[2];
      }
    }

#pragma unroll 1
    for (int g = 0; g < 4; ++g) {        // 12 full chunks = 4 groups x 3 phases
      const int base = lx + 12 * g + 12;
      syncstage();
      if (act) full_chunk<0>(v4, w4, woff, base + 0, hbuf + bcur * HCH, off0, off1, acc, lds);
      adv();
      syncstage();
      if (act) full_chunk<1>(v4, w4, woff, base + 4, hbuf + bcur * HCH, off0, off1, acc, lds);
      adv();
      syncstage();
      if (act) full_chunk<2>(v4, w4, woff, base + 8, hbuf + bcur * HCH, off0, off1, acc, lds);
      adv();
    }

    // Epilogue chunk (cc=12): j = 48,49,50; phase-0 window layout.
    syncstage();
    if (act) {
      const float* hb = hbuf + bcur * HCH;
      const float4 e0a = *reinterpret_cast<const float4*>(hb + off0);
      const float4 e0b = *reinterpret_cast<const float4*>(hb + off1);
      const float4 e1a = *reinterpret_cast<const float4*>(hb + 512 + off0);
      const float4 e1b = *reinterpret_cast<const float4*>(hb + 512 + off1);
      const float4 e2a = *reinterpret_cast<const float4*>(hb + 1024 + off0);
      const float4 e2b = *reinterpret_cast<const float4*>(hb + 1024 + off1);
      fma_jtap<0, 0>(v4, w4, e0a, e0b, acc);
      fma_jtap<0, 1>(v4, w4, e1a, e1b, acc);
      fma_jtap<0, 2>(v4, w4, e2a, e2b, acc);
    }
    adv();
  }

  // ---- Reduce the 4 i-split partials (waves 1..3 -> LDS inp region, wave 0 adds & stores)
  __syncthreads();   // all compute done; safe to reuse inp region (full drain ok here)
  if (s > 0) {
    float* p = &lds[((s - 1) * 64 + ty * NTX + tx) * R];
#pragma unroll
    for (int rx = 0; rx < R; ++rx) p[rx] = acc[rx];
  }
  __syncthreads();
  if (s == 0) {
#pragma unroll
    for (int g = 0; g < 3; ++g) {
      const float* p = &lds[(g * 64 + ty * NTX + tx) * R];
#pragma unroll
      for (int rx = 0; rx < R; ++rx) acc[rx] += p[rx];
    }
    float* o = out + (((size_t)(b * NC + c)) * HH + yg) * WW + xg;
    *reinterpret_cast<float4*>(o)     = make_float4(acc[0], acc[1], acc[2], acc[3]);
    *reinterpret_cast<float4*>(o + 4) = make_float4(acc[4], acc[5], acc[6], acc[7]);
  }
}

extern "C" void kernel_launch(void* const* d_in, const int* in_sizes, int n_in,
                              void* d_out, int out_size, void* d_ws, size_t ws_size,
                              hipStream_t stream) {
  const float* inp   = (const float*)d_in[0];
  const float* vert  = (const float*)d_in[1];
  const float* horiz = (const float*)d_in[2];
  float* out = (float*)d_out;

  dim3 grid(WW / TILE_W, HH / TILE_H, NB * NC);   // 4 x 32 x 6 = 768 blocks x 256 threads
  sepconv_kernel<<<grid, NTHREADS, 0, stream>>>(inp, vert, horiz, out);
}